// Round 5
// baseline (34318.976 us; speedup 1.0000x reference)
//
#include <hip/hip_runtime.h>

#define NTOK 32768   // input rows
#define KEMB 8192    // embedding codes
#define DIM  256     // feature dim

// ---------------------------------------------------------------------------
// numpy-pairwise fp32 sum of squares of a 256-element contiguous row.
// numpy pairwise_sum(a,256) = pw(a,128) + pw(a+128,128); each 128-block uses
// 8 accumulators r_j = a[j] + a[j+8] + ... + a[j+120] (16 sequential fp32
// adds of fp32-rounded squares), combined ((r0+r1)+(r2+r3))+((r4+r5)+(r6+r7)).
// One 16-lane group per row: lane l -> j = l&7, half = l>>3. The shfl_xor
// 1,2,4 butterfly reproduces the exact 8-way combine tree; xor 8 adds the
// two 128-blocks. All adds via __fadd_rn (unfusable, IEEE fp32).
// ---------------------------------------------------------------------------
__global__ __launch_bounds__(256) void rowsq_np(const float* __restrict__ src,
                                                float* __restrict__ dst,
                                                int nrows) {
  int g = (blockIdx.x * 256 + threadIdx.x) >> 4;   // row id
  if (g >= nrows) return;
  int l = threadIdx.x & 15;
  int j = l & 7, half = l >> 3;
  const float* row = src + (size_t)g * DIM + half * 128 + j;
  float s = 0.f;
  #pragma unroll
  for (int i = 0; i < 16; ++i) {
    float v = row[8 * i];
    s = __fadd_rn(s, __fmul_rn(v, v));   // fp32 square then fp32 add, unfused
  }
  s = __fadd_rn(s, __shfl_xor(s, 1));    // (r0+r1), (r2+r3), ...
  s = __fadd_rn(s, __shfl_xor(s, 2));    // ((r0+r1)+(r2+r3)), ...
  s = __fadd_rn(s, __shfl_xor(s, 4));    // full 8-way block sum
  s = __fadd_rn(s, __shfl_xor(s, 8));    // left128 + right128
  if (l == 0) dst[g] = s;
}

// ---------------------------------------------------------------------------
// Exhaustive argmin under numpy-float32-faithful semantics:
//   d[n,k] = fp32( fp32(A[n] + B[k]) - fp32(2 * C32[n,k]) )
// where A,B are numpy-pairwise fp32 row sums (above), C32 = fp32 rounding of
// the exact (fp64) dot x_n . e_k  (matches BLAS sgemm to ~1e-9, far below the
// ulp(256)=3e-5 grid that creates the ties). Argmin: strict <, ascending k
// == numpy first-min tie semantics. 4 waves/block, 2 rows/wave.
// ---------------------------------------------------------------------------
__global__ __launch_bounds__(256) void exhaustive_np(
    const float* __restrict__ x,
    const float* __restrict__ e,
    const float* __restrict__ An,
    const float* __restrict__ Bk,
    float* __restrict__ out,
    double* __restrict__ partials) {
  __shared__ __align__(16) float4 Ech[32][64];  // 32 codes x 256 f32 = 32 KB
  __shared__ float Bs[32];
  __shared__ double wsum[8];

  const int tid = threadIdx.x;
  const int lane = tid & 63, wid = tid >> 6;
  const int n0 = blockIdx.x * 8 + wid * 2;      // this wave's rows: n0, n0+1

  float4 xa = ((const float4*)x)[(size_t)n0 * 64 + lane];
  float4 xb = ((const float4*)x)[(size_t)(n0 + 1) * 64 + lane];
  double xd0[4] = {xa.x, xa.y, xa.z, xa.w};
  double xd1[4] = {xb.x, xb.y, xb.z, xb.w};
  const float A0 = An[n0], A1 = An[n0 + 1];

  float bd0 = INFINITY, bd1 = INFINITY;
  int bi0 = 0, bi1 = 0;

  for (int c = 0; c < KEMB / 32; ++c) {
    __syncthreads();
    #pragma unroll
    for (int t = 0; t < 8; ++t) {
      int idx = t * 256 + tid;                  // 0..2047
      int row = idx >> 6, col = idx & 63;
      Ech[row][col] = ((const float4*)e)[(size_t)(c * 32 + row) * 64 + col];
    }
    if (tid < 32) Bs[tid] = Bk[c * 32 + tid];
    __syncthreads();

    for (int kk = 0; kk < 32; ++kk) {
      float4 ev = Ech[kk][lane];
      double e0 = ev.x, e1 = ev.y, e2 = ev.z, e3 = ev.w;
      double d0 = e0 * xd0[0] + e1 * xd0[1] + e2 * xd0[2] + e3 * xd0[3];
      double d1 = e0 * xd1[0] + e1 * xd1[1] + e2 * xd1[2] + e3 * xd1[3];
      #pragma unroll
      for (int sh = 1; sh < 64; sh <<= 1) {
        d0 += __shfl_xor(d0, sh);
        d1 += __shfl_xor(d1, sh);
      }
      int k = c * 32 + kk;
      // numpy fp32 pipeline: t1 = A + B; t2 = 2*C32; d = t1 - t2 (all fp32)
      float c320 = (float)d0;
      float c321 = (float)d1;
      float dd0 = __fsub_rn(__fadd_rn(A0, Bs[kk]), __fmul_rn(2.0f, c320));
      float dd1 = __fsub_rn(__fadd_rn(A1, Bs[kk]), __fmul_rn(2.0f, c321));
      if (dd0 < bd0) { bd0 = dd0; bi0 = k; }    // strict < : first-min ties
      if (dd1 < bd1) { bd1 = dd1; bi1 = k; }
    }
  }

  // ---- outputs for the wave's 2 rows (original-precision data) ----
  #pragma unroll
  for (int r = 0; r < 2; ++r) {
    int n = n0 + r;
    int bi = r ? bi1 : bi0;
    float4 q = ((const float4*)e)[(size_t)bi * 64 + lane];
    ((float4*)out)[(size_t)n * 64 + lane] = q;   // quantized_st == quantized
    float4 xo = r ? xb : xa;
    double a0 = (double)q.x - (double)xo.x;
    double a1 = (double)q.y - (double)xo.y;
    double a2 = (double)q.z - (double)xo.z;
    double a3 = (double)q.w - (double)xo.w;
    double l = a0 * a0 + a1 * a1 + a2 * a2 + a3 * a3;
    #pragma unroll
    for (int sh = 1; sh < 64; sh <<= 1) l += __shfl_xor(l, sh);
    if (lane == 0) {
      wsum[wid * 2 + r] = l;
      out[(size_t)NTOK * DIM + 1 + n] = (float)bi;   // indices region
    }
  }
  __syncthreads();
  if (tid == 0) {
    double s = 0;
    #pragma unroll
    for (int i = 0; i < 8; ++i) s += wsum[i];
    partials[blockIdx.x] = s;
  }
}

// ---------------- finalize: deterministic loss reduction ----------------
__global__ __launch_bounds__(256) void finalize(const double* __restrict__ partials,
                                                float* __restrict__ out) {
  __shared__ double sd[256];
  double s = 0;
  for (int i = threadIdx.x; i < NTOK / 8; i += 256) s += partials[i];
  sd[threadIdx.x] = s;
  __syncthreads();
  for (int st = 128; st > 0; st >>= 1) {
    if (threadIdx.x < st) sd[threadIdx.x] += sd[threadIdx.x + st];
    __syncthreads();
  }
  if (threadIdx.x == 0)
    out[(size_t)NTOK * DIM] = (float)(1.25 * sd[0] / ((double)NTOK * (double)DIM));
}

extern "C" void kernel_launch(void* const* d_in, const int* in_sizes, int n_in,
                              void* d_out, int out_size, void* d_ws, size_t ws_size,
                              hipStream_t stream) {
  const float* x = (const float*)d_in[0];   // [32768, 256]
  const float* e = (const float*)d_in[1];   // [8192, 256]
  float* out = (float*)d_out;

  // workspace layout (tiny)
  char* w = (char*)d_ws;
  float* An        = (float*)(w + 0);           // 131,072 B
  float* Bk        = (float*)(w + 131072);      //  32,768 B
  double* partials = (double*)(w + 163840);     //  32,768 B

  rowsq_np<<<NTOK / 16, 256, 0, stream>>>(x, An, NTOK);
  rowsq_np<<<KEMB / 16, 256, 0, stream>>>(e, Bk, KEMB);

  exhaustive_np<<<NTOK / 8, 256, 0, stream>>>(x, e, An, Bk, out, partials);
  finalize<<<1, 256, 0, stream>>>(partials, out);
}